// Round 17
// baseline (18.792 us; speedup 1.0000x reference)
//
#include <hip/hip_runtime.h>
#include <hip/hip_bf16.h>

typedef unsigned short ushort_t;
typedef unsigned int uint_t;
typedef __attribute__((ext_vector_type(8))) short short8;
typedef __attribute__((ext_vector_type(4))) float f32x4;

#define IN_DIM 256
#define OUT_DIM 256
#define BATCH 512
#define NSPL 11
#define KSLOT 12
#define KDIM (IN_DIM * KSLOT)    // 3072
#define BKU 384                  // ushorts per row per chunk (32 inputs x 12)
#define NCHUNK 8

__device__ __forceinline__ uint_t pk2(float lo, float hi) {
  __hip_bfloat162 h = __float22bfloat162_rn(make_float2(lo, hi));  // v_cvt_pk_bf16_f32, RNE
  union { __hip_bfloat162 h2; uint_t u; } c; c.h2 = h;
  return c.u;
}

// ---- Kernel 1: build W[256][3072] (bf16, KSLOT-interleaved) ONCE ----
__global__ __launch_bounds__(256) void build_w(const float* __restrict__ coef,
                                               const float* __restrict__ rw,
                                               const float* __restrict__ uw,
                                               ushort_t* __restrict__ W) {
  __shared__ float rowc[IN_DIM * NSPL];            // 11.3 KB: one o-row of coef
  const int o = blockIdx.x;
  const int t = threadIdx.x;

  const float* src = coef + (size_t)o * IN_DIM * NSPL;     // 2816 floats, coalesced
#pragma unroll
  for (int j = 0; j < 11; ++j) rowc[t + j * 256] = src[t + j * 256];
  __syncthreads();

  const float us = uw[o * IN_DIM + t];
  const float r  = rw[o * IN_DIM + t];
  const float* c = &rowc[t * NSPL];                 // stride 11: bank-benign
  uint_t* dst = (uint_t*)(W + (size_t)o * KDIM + t * KSLOT);
  dst[0] = pk2(us * c[0], us * c[1]);
  dst[1] = pk2(us * c[2], us * c[3]);
  dst[2] = pk2(us * c[4], us * c[5]);
  dst[3] = pk2(us * c[6], us * c[7]);
  dst[4] = pk2(us * c[8], us * c[9]);
  dst[5] = pk2(us * c[10], r);
}

// A-cell: closed-form cubic B-spline, scatter-written at swizzled LDS addresses.
// swz = (row&7)<<3 (XOR of ushort-index bits 3..5): aligned-8 granules move as
// units, so the three 8B zero-fills stay contiguous; single-ushort scatters are
// XOR'd individually. OOB slots dump into scratch (dead `red` buffer).
__device__ __forceinline__ void packA_swz(ushort_t* rowbase, int cellu, int swz,
                                          ushort_t* dumpp, float xf) {
  const float t = (xf + 1.75f) * 4.0f;
  const float fJ = floorf(t);
  const int J = (int)fJ;
  const float u = t - fJ;
  const float u2 = u * u, u3 = u2 * u, um = 1.0f - u;
  const float n0 = um * um * um * (1.0f / 6.0f);                        // slot J-3
  const float n1 = 0.5f * u3 - u2 + (4.0f / 6.0f);                      // slot J-2
  const float n2 = -0.5f * u3 + 0.5f * u2 + 0.5f * u + (1.0f / 6.0f);   // slot J-1
  const float n3 = u3 * (1.0f / 6.0f);                                  // slot J
  const float silu = xf / (1.0f + __expf(-xf));

  // zero the 12-slot cell: 3 x 8B at aligned-4 ushort offsets (swizzle-safe units)
  *(unsigned long long*)&rowbase[(cellu + 0) ^ swz] = 0ull;
  *(unsigned long long*)&rowbase[(cellu + 4) ^ swz] = 0ull;
  *(unsigned long long*)&rowbase[(cellu + 8) ^ swz] = 0ull;

  const uint_t p01 = pk2(n0, n1);
  const uint_t p23 = pk2(n2, n3);
  const uint_t psl = pk2(silu, silu);

  const int base = J - 3;
  ushort_t* w0 = ((unsigned)(base + 0) <= 10u) ? &rowbase[(cellu + base + 0) ^ swz] : (dumpp + 0);
  ushort_t* w1 = ((unsigned)(base + 1) <= 10u) ? &rowbase[(cellu + base + 1) ^ swz] : (dumpp + 1);
  ushort_t* w2 = ((unsigned)(base + 2) <= 10u) ? &rowbase[(cellu + base + 2) ^ swz] : (dumpp + 2);
  ushort_t* w3 = ((unsigned)(base + 3) <= 10u) ? &rowbase[(cellu + base + 3) ^ swz] : (dumpp + 3);
  *w0 = (ushort_t)p01;
  *w1 = (ushort_t)(p01 >> 16);
  *w2 = (ushort_t)p23;
  *w3 = (ushort_t)(p23 >> 16);
  rowbase[(cellu + 11) ^ swz] = (ushort_t)psl;
}

// ---- Kernel 2: out = A(x) · Wᵀ. 512 blocks x 4 waves; 16x16 tile.
// A built in-register->LDS per chunk (x stashed in 16 regs, NO global A traffic);
// W staged with depth-2 register prefetch (T14); T2 XOR-swizzled LDS; split-K. ----
__global__ __launch_bounds__(256, 3) void gemm(const float* __restrict__ x,
                                               const ushort_t* __restrict__ W,
                                               float* __restrict__ out) {
  __shared__ __attribute__((aligned(16))) ushort_t As[2][16 * BKU];   // 24.6 KB
  __shared__ __attribute__((aligned(16))) ushort_t Ws[2][16 * BKU];   // 24.6 KB
  __shared__ __attribute__((aligned(16))) f32x4 red[3][64];           // 3 KB (dump scratch in loop)

  const int tid = threadIdx.x;
  const int lane = tid & 63;
  const int w = tid >> 6;                          // wave 0..3 = K-slice owner
  const int B = blockIdx.x;
  const int mt = B >> 4;
  const int nt = ((B & 7) << 1) | ((B >> 3) & 1);  // XCD-aware (bijective, 512%8==0)
  const int b0 = mt * 16, o0 = nt * 16;
  const int mn = lane & 15;
  const int klane = (lane >> 4) * 8;

  const int row = tid >> 4;                        // 0..15: tile row this thread builds
  const int i0 = tid & 15;                         // cells (row,i0), (row,i0+16) per chunk
  const int aswz = (row & 7) << 3;

  // prologue: stash this thread's 16 x-values (2 per chunk), coalesced per 16 lanes
  float xreg[16];
  const float* xp = x + (size_t)(b0 + row) * IN_DIM;
#pragma unroll
  for (int c2 = 0; c2 < 8; ++c2) {
    xreg[2 * c2]     = xp[32 * c2 + i0];
    xreg[2 * c2 + 1] = xp[32 * c2 + i0 + 16];
  }

  // W staging geometry (chunk-invariant): wave w covers 3 x 512-ushort slabs
  int srcOff[3], ldsOff[3];
#pragma unroll
  for (int i = 0; i < 3; ++i) {
    const int F = ((w * 3 + i) * 64 + lane) * 8;
    const int rowi = F / BKU;
    const int coli = F % BKU;
    srcOff[i] = rowi * KDIM + coli;
    ldsOff[i] = rowi * BKU + (coli ^ ((rowi & 7) << 3));
  }
  const ushort_t* Wp = W + (size_t)o0 * KDIM;

  const int mrow = mn * BKU;
  const int msw = (mn & 7) << 3;

  f32x4 acc = {0.f, 0.f, 0.f, 0.f};
  short8 sa0, sa1, sa2, sb0, sb1, sb2;             // two W register stages

#define ISSUE_A(C) { const int kb=(C)*BKU; \
    sa0 = *(const short8*)(Wp+srcOff[0]+kb); \
    sa1 = *(const short8*)(Wp+srcOff[1]+kb); \
    sa2 = *(const short8*)(Wp+srcOff[2]+kb); }
#define ISSUE_B(C) { const int kb=(C)*BKU; \
    sb0 = *(const short8*)(Wp+srcOff[0]+kb); \
    sb1 = *(const short8*)(Wp+srcOff[1]+kb); \
    sb2 = *(const short8*)(Wp+srcOff[2]+kb); }
#define COMMIT_A(BUF) { *(short8*)&Ws[BUF][ldsOff[0]] = sa0; \
    *(short8*)&Ws[BUF][ldsOff[1]] = sa1; *(short8*)&Ws[BUF][ldsOff[2]] = sa2; }
#define COMMIT_B(BUF) { *(short8*)&Ws[BUF][ldsOff[0]] = sb0; \
    *(short8*)&Ws[BUF][ldsOff[1]] = sb1; *(short8*)&Ws[BUF][ldsOff[2]] = sb2; }

#define APACK(C, BUF) { ushort_t* rb = &As[BUF][row * BKU]; \
    ushort_t* dp = ((ushort_t*)red) + tid * 4; \
    packA_swz(rb, i0 * KSLOT, aswz, dp, xreg[2 * (C)]); \
    packA_swz(rb, (i0 + 16) * KSLOT, aswz, dp, xreg[2 * (C) + 1]); }

#define MFMA3(BUF) { _Pragma("unroll") \
    for (int q = 0; q < 3; ++q) { \
      const int kidx = w * 96 + q * 32 + klane; \
      const int idx = mrow + (kidx ^ msw); \
      short8 af  = *(const short8*)&As[BUF][idx]; \
      short8 bfr = *(const short8*)&Ws[BUF][idx]; \
      acc = __builtin_amdgcn_mfma_f32_16x16x32_bf16(af, bfr, acc, 0, 0, 0); }}

  // prologue: chunk 0 fully built; chunk 1 W-loads in flight
  ISSUE_A(0)
  COMMIT_A(0)
  APACK(0, 0)
  ISSUE_B(1)
  __syncthreads();

#pragma unroll
  for (int cc = 0; cc < 4; ++cc) {
    // even phase p=2cc (buffer 0)
    MFMA3(0)
    if (cc < 3) { ISSUE_A(2 * cc + 2) }            // W loads 2 chunks ahead
    APACK(2 * cc + 1, 1)                           // A build (VALU) hides W latency
    COMMIT_B(1)                                    // waits loads issued last phase
    __syncthreads();

    // odd phase p=2cc+1 (buffer 1)
    MFMA3(1)
    if (cc < 3) {
      ISSUE_B(2 * cc + 3)
      APACK(2 * cc + 2, 0)
      COMMIT_A(0)
    }
    __syncthreads();
  }

  // cross-wave split-K reduce, then write
  if (w > 0) red[w - 1][lane] = acc;
  __syncthreads();

  if (w == 0) {
    const f32x4 t0 = red[0][lane];
    const f32x4 t1 = red[1][lane];
    const f32x4 t2 = red[2][lane];
#pragma unroll
    for (int q = 0; q < 4; ++q) acc[q] += t0[q] + t1[q] + t2[q];

    // C/D layout (HW-verified): col = lane&15, row = (lane>>4)*4 + reg
    const int col = o0 + mn;
    const int rbase = b0 + (lane >> 4) * 4;
#pragma unroll
    for (int r = 0; r < 4; ++r) {
      out[(size_t)(rbase + r) * OUT_DIM + col] = acc[r];
    }
  }
}

extern "C" void kernel_launch(void* const* d_in, const int* in_sizes, int n_in,
                              void* d_out, int out_size, void* d_ws, size_t ws_size,
                              hipStream_t stream) {
  const float* x    = (const float*)d_in[0];
  const float* coef = (const float*)d_in[1];
  const float* rw   = (const float*)d_in[2];
  const float* uw   = (const float*)d_in[3];
  float* out = (float*)d_out;

  ushort_t* W = (ushort_t*)d_ws;                   // 256*3072*2 = 1.5 MB

  build_w<<<OUT_DIM, 256, 0, stream>>>(coef, rw, uw, W);
  gemm<<<512, 256, 0, stream>>>(x, W, out);
}

// Round 18
// 17.724 us; speedup vs baseline: 1.0603x; 1.0603x over previous
//
#include <hip/hip_runtime.h>
#include <hip/hip_bf16.h>

typedef unsigned short ushort_t;
typedef unsigned int uint_t;
typedef __attribute__((ext_vector_type(8))) short short8;
typedef __attribute__((ext_vector_type(4))) float f32x4;

#define IN_DIM 256
#define OUT_DIM 256
#define BATCH 512
#define NSPL 11
#define KSLOT 12
#define KDIM (IN_DIM * KSLOT)    // 3072
#define BKU 384                  // ushorts per row per chunk (32 inputs x 12)
#define NCHUNK 8

__device__ __forceinline__ uint_t pk2(float lo, float hi) {
  __hip_bfloat162 h = __float22bfloat162_rn(make_float2(lo, hi));  // v_cvt_pk_bf16_f32, RNE
  union { __hip_bfloat162 h2; uint_t u; } c; c.h2 = h;
  return c.u;
}

// ---- Kernel 1: build A[512][3072] and W[256][3072] (bf16, KSLOT-interleaved) ONCE ----
__global__ __launch_bounds__(256) void build_aw(const float* __restrict__ x,
                                                const float* __restrict__ coef,
                                                const float* __restrict__ rw,
                                                const float* __restrict__ uw,
                                                ushort_t* __restrict__ A,
                                                ushort_t* __restrict__ W) {
  __shared__ float rowc[IN_DIM * NSPL];            // 11.3 KB: one o-row of coef
  const int bx = blockIdx.x;
  const int t = threadIdx.x;

  if (bx < BATCH) {
    // A row b=bx, cell i=t: closed-form cubic B-spline + silu slot
    const float xf = x[bx * IN_DIM + t];
    const float tt = (xf + 1.75f) * 4.0f;
    const float fJ = floorf(tt);
    const int J = (int)fJ;
    const float u = tt - fJ;
    const float u2 = u * u, u3 = u2 * u, um = 1.0f - u;
    const float n0 = um * um * um * (1.0f / 6.0f);                        // slot J-3
    const float n1 = 0.5f * u3 - u2 + (4.0f / 6.0f);                      // slot J-2
    const float n2 = -0.5f * u3 + 0.5f * u2 + 0.5f * u + (1.0f / 6.0f);   // slot J-1
    const float n3 = u3 * (1.0f / 6.0f);                                  // slot J
    const float silu = xf / (1.0f + __expf(-xf));

    float v[12];
#pragma unroll
    for (int g = 0; g < NSPL; ++g) {
      float val = 0.0f;
      val = (J == g + 3) ? n0 : val;
      val = (J == g + 2) ? n1 : val;
      val = (J == g + 1) ? n2 : val;
      val = (J == g    ) ? n3 : val;
      v[g] = val;
    }
    v[11] = silu;

    uint_t* dst = (uint_t*)(A + (size_t)bx * KDIM + t * KSLOT);
#pragma unroll
    for (int j = 0; j < 6; ++j) dst[j] = pk2(v[2 * j], v[2 * j + 1]);
  } else {
    // W row o=bx-512: coalesced row-stage through LDS, then per-cell pack
    const int o = bx - BATCH;
    const float* src = coef + (size_t)o * IN_DIM * NSPL;     // 2816 floats
#pragma unroll
    for (int j = 0; j < 11; ++j) rowc[t + j * 256] = src[t + j * 256];
    __syncthreads();

    const float us = uw[o * IN_DIM + t];
    const float r  = rw[o * IN_DIM + t];
    const float* c = &rowc[t * NSPL];               // stride 11: bank-benign
    uint_t* dst = (uint_t*)(W + (size_t)o * KDIM + t * KSLOT);
    dst[0] = pk2(us * c[0], us * c[1]);
    dst[1] = pk2(us * c[2], us * c[3]);
    dst[2] = pk2(us * c[4], us * c[5]);
    dst[3] = pk2(us * c[6], us * c[7]);
    dst[4] = pk2(us * c[8], us * c[9]);
    dst[5] = pk2(us * c[10], r);
  }
}

// ---- Kernel 2: out = A · Wᵀ. 512 blocks x 4 waves; 16x16 tile; double-buffered
// LDS (T2 XOR-swizzle) with DEPTH-2 register staging: loads for chunk c+2 issue
// at phase c, commit (pure ds_write, data long since landed) at phase c+1.
// Split-K across waves, one barrier per phase (last phase's trimmed). ----
__global__ __launch_bounds__(256, 3) void gemm(const ushort_t* __restrict__ A,
                                               const ushort_t* __restrict__ W,
                                               float* __restrict__ out) {
  __shared__ __attribute__((aligned(16))) ushort_t As[2][16 * BKU];   // 24.6 KB
  __shared__ __attribute__((aligned(16))) ushort_t Ws[2][16 * BKU];   // 24.6 KB
  __shared__ f32x4 red[3][64];

  const int tid = threadIdx.x;
  const int lane = tid & 63;
  const int w = tid >> 6;                          // wave 0..3 = K-slice owner
  const int B = blockIdx.x;
  const int mt = B >> 4;
  const int nt = ((B & 7) << 1) | ((B >> 3) & 1);  // XCD-aware (bijective, 512%8==0)
  const int b0 = mt * 16, o0 = nt * 16;
  const int mn = lane & 15;
  const int klane = (lane >> 4) * 8;

  // Staging geometry (chunk-invariant): wave w covers 3 x 512-ushort slabs.
  int srcOff[3], ldsOff[3];
#pragma unroll
  for (int i = 0; i < 3; ++i) {
    const int F = ((w * 3 + i) * 64 + lane) * 8;
    const int rowi = F / BKU;                      // 0..15
    const int coli = F % BKU;
    srcOff[i] = rowi * KDIM + coli;                // global: linear, coalesced
    ldsOff[i] = rowi * BKU + (coli ^ ((rowi & 7) << 3));   // T2 swizzle (ushort units)
  }
  const ushort_t* Ap = A + (size_t)b0 * KDIM;
  const ushort_t* Wp = W + (size_t)o0 * KDIM;

  // MFMA read offsets (swizzled to match)
  const int mrow = mn * BKU;
  const int msw = (mn & 7) << 3;

  f32x4 acc = {0.f, 0.f, 0.f, 0.f};

  // two named register stages (rule #20: all static)
  short8 s0a0, s0a1, s0a2, s0w0, s0w1, s0w2;
  short8 s1a0, s1a1, s1a2, s1w0, s1w1, s1w2;

#define ISSUE_S0(C) { const int kb = (C) * BKU;                               \
    s0a0 = *(const short8*)(Ap + srcOff[0] + kb);                             \
    s0a1 = *(const short8*)(Ap + srcOff[1] + kb);                             \
    s0a2 = *(const short8*)(Ap + srcOff[2] + kb);                             \
    s0w0 = *(const short8*)(Wp + srcOff[0] + kb);                             \
    s0w1 = *(const short8*)(Wp + srcOff[1] + kb);                             \
    s0w2 = *(const short8*)(Wp + srcOff[2] + kb); }
#define ISSUE_S1(C) { const int kb = (C) * BKU;                               \
    s1a0 = *(const short8*)(Ap + srcOff[0] + kb);                             \
    s1a1 = *(const short8*)(Ap + srcOff[1] + kb);                             \
    s1a2 = *(const short8*)(Ap + srcOff[2] + kb);                             \
    s1w0 = *(const short8*)(Wp + srcOff[0] + kb);                             \
    s1w1 = *(const short8*)(Wp + srcOff[1] + kb);                             \
    s1w2 = *(const short8*)(Wp + srcOff[2] + kb); }
#define COMMIT_S0(BUF) {                                                      \
    *(short8*)&As[BUF][ldsOff[0]] = s0a0;                                     \
    *(short8*)&As[BUF][ldsOff[1]] = s0a1;                                     \
    *(short8*)&As[BUF][ldsOff[2]] = s0a2;                                     \
    *(short8*)&Ws[BUF][ldsOff[0]] = s0w0;                                     \
    *(short8*)&Ws[BUF][ldsOff[1]] = s0w1;                                     \
    *(short8*)&Ws[BUF][ldsOff[2]] = s0w2; }
#define COMMIT_S1(BUF) {                                                      \
    *(short8*)&As[BUF][ldsOff[0]] = s1a0;                                     \
    *(short8*)&As[BUF][ldsOff[1]] = s1a1;                                     \
    *(short8*)&As[BUF][ldsOff[2]] = s1a2;                                     \
    *(short8*)&Ws[BUF][ldsOff[0]] = s1w0;                                     \
    *(short8*)&Ws[BUF][ldsOff[1]] = s1w1;                                     \
    *(short8*)&Ws[BUF][ldsOff[2]] = s1w2; }

#define MFMA3(BUF) { _Pragma("unroll")                                        \
    for (int q = 0; q < 3; ++q) {                                             \
      const int kidx = w * 96 + q * 32 + klane;                               \
      const int idx = mrow + (kidx ^ msw);                                    \
      short8 af  = *(const short8*)&As[BUF][idx];                             \
      short8 bfr = *(const short8*)&Ws[BUF][idx];                             \
      acc = __builtin_amdgcn_mfma_f32_16x16x32_bf16(af, bfr, acc, 0, 0, 0); }}

  // prologue: chunk 0 staged+committed (one unavoidable stall); chunk 1 in flight
  ISSUE_S0(0)
  COMMIT_S0(0)
  ISSUE_S1(1)
  __syncthreads();

  // chunk c lives in buffer c&1. stage S0 = even chunks, S1 = odd chunks.
#pragma unroll
  for (int cc = 0; cc < 4; ++cc) {
    // even phase p=2cc (consume buf0 = chunk 2cc)
    if (cc < 3) { ISSUE_S0(2 * cc + 2) }   // loads for chunk 2cc+2 (commit next phase)
    MFMA3(0)
    COMMIT_S1(1)                           // chunk 2cc+1: loaded a full phase ago
    __syncthreads();

    // odd phase p=2cc+1 (consume buf1 = chunk 2cc+1)
    if (cc < 3) {
      ISSUE_S1(2 * cc + 3)                 // loads for chunk 2cc+3
      MFMA3(1)
      COMMIT_S0(0)                         // chunk 2cc+2: loaded last phase
      __syncthreads();
    } else {
      MFMA3(1)                             // last phase: no commit, barrier folds into reduce
    }
  }

  // cross-wave split-K reduce, then write
  if (w > 0) red[w - 1][lane] = acc;
  __syncthreads();

  if (w == 0) {
    const f32x4 t0 = red[0][lane];
    const f32x4 t1 = red[1][lane];
    const f32x4 t2 = red[2][lane];
#pragma unroll
    for (int q = 0; q < 4; ++q) acc[q] += t0[q] + t1[q] + t2[q];

    // C/D layout (HW-verified): col = lane&15, row = (lane>>4)*4 + reg
    const int col = o0 + mn;
    const int rbase = b0 + (lane >> 4) * 4;
#pragma unroll
    for (int r = 0; r < 4; ++r) {
      out[(size_t)(rbase + r) * OUT_DIM + col] = acc[r];
    }
  }
}

extern "C" void kernel_launch(void* const* d_in, const int* in_sizes, int n_in,
                              void* d_out, int out_size, void* d_ws, size_t ws_size,
                              hipStream_t stream) {
  const float* x    = (const float*)d_in[0];
  const float* coef = (const float*)d_in[1];
  const float* rw   = (const float*)d_in[2];
  const float* uw   = (const float*)d_in[3];
  float* out = (float*)d_out;

  ushort_t* A = (ushort_t*)d_ws;                             // 512*3072*2 = 3.0 MB
  ushort_t* W = A + (size_t)BATCH * KDIM;                    // 256*3072*2 = 1.5 MB

  build_aw<<<BATCH + OUT_DIM, 256, 0, stream>>>(x, coef, rw, uw, A, W);
  gemm<<<512, 256, 0, stream>>>(A, W, out);
}